// Round 1
// baseline (969.352 us; speedup 1.0000x reference)
//
#include <hip/hip_runtime.h>
#include <math.h>

constexpr int D = 32000;
constexpr int BLOCK = 1024;
constexpr int NW = BLOCK / 64;                    // 16 waves
constexpr int FULL4 = D / (4 * BLOCK);            // 7 full float4 rounds
constexpr int REM_ELEMS = D - FULL4 * 4 * BLOCK;  // 3328
constexpr int REM_THREADS = REM_ELEMS / 4;        // 832 (= 13 waves exactly)
constexpr int NV = FULL4 + 1;                     // 8 float4 per thread
constexpr int CAP = 2048;
constexpr int NITER = 50;
constexpr int PERSIST = 256;                      // 1 persistent block per CU

__device__ __forceinline__ float wave_sum(float s) {
#pragma unroll
  for (int o = 32; o > 0; o >>= 1) s += __shfl_xor(s, o, 64);
  return s;
}

// Workgroup barrier that does NOT drain vmcnt: keeps the next-row prefetch
// loads in flight. (__syncthreads() would emit s_waitcnt vmcnt(0) before
// s_barrier and serialize the pipeline.) lgkmcnt(0) gives LDS visibility.
__device__ __forceinline__ void bar_lds() {
  asm volatile("s_waitcnt lgkmcnt(0)" ::: "memory");
  __builtin_amdgcn_s_barrier();
  asm volatile("" ::: "memory");
}

__device__ __forceinline__ void process_row(
    float4 (&cur)[NV], float4 (&nxt)[NV],
    const float* __restrict__ Xnext, bool pf,
    float* __restrict__ Or,
    float* s_cand, float* s_red, int* s_cnt, int par,
    int t, int lane, int wid, bool has_rem) {
  // ---- 1) issue prefetch of the NEXT row into nxt; these global loads stay
  //         in flight across all compute/reductions below (raw barriers) ----
  if (pf) {
    const float4* Xn4 = reinterpret_cast<const float4*>(Xnext);
#pragma unroll
    for (int j = 0; j < FULL4; ++j) nxt[j] = Xn4[t + BLOCK * j];
    if (has_rem)
      nxt[FULL4] = Xn4[FULL4 * BLOCK + t];
    else
      nxt[FULL4] = make_float4(-INFINITY, -INFINITY, -INFINITY, -INFINITY);
  }

  // ---- 2) row max: local -> wave shuffle -> LDS across 16 waves ----
  float m = -INFINITY;
#pragma unroll
  for (int j = 0; j < NV; ++j)
    m = fmaxf(m, fmaxf(fmaxf(cur[j].x, cur[j].y), fmaxf(cur[j].z, cur[j].w)));
#pragma unroll
  for (int o = 32; o > 0; o >>= 1) m = fmaxf(m, __shfl_xor(m, o, 64));
  if (lane == 0) s_red[wid] = m;
  bar_lds();
  float rowmax = s_red[0];
#pragma unroll
  for (int j = 1; j < NW; ++j) rowmax = fmaxf(rowmax, s_red[j]);

  // ---- 3) gather candidates x > rowmax-1 (only these can contribute:
  //         tau_m > tau_lo >= rowmax-1 for all 50 iterations) ----
  const float thresh = rowmax - 1.0f;
#pragma unroll
  for (int j = 0; j < NV; ++j) {
    const float a0 = cur[j].x, a1 = cur[j].y, a2 = cur[j].z, a3 = cur[j].w;
    if (a0 > thresh) { int i = atomicAdd(&s_cnt[par], 1); if (i < CAP) s_cand[i] = a0; }
    if (a1 > thresh) { int i = atomicAdd(&s_cnt[par], 1); if (i < CAP) s_cand[i] = a1; }
    if (a2 > thresh) { int i = atomicAdd(&s_cnt[par], 1); if (i < CAP) s_cand[i] = a2; }
    if (a3 > thresh) { int i = atomicAdd(&s_cnt[par], 1); if (i < CAP) s_cand[i] = a3; }
  }
  bar_lds();
  const int n = s_cnt[par];  // block-uniform (all atomics pre-barrier)
  // Reset the OTHER parity's counter for the next row. Safe: its previous
  // readers all finished one full barrier-pair ago.
  if (t == 0) s_cnt[par ^ 1] = 0;

  float tau, inv;
  if (n <= 64) {
    // ---- fast path: every wave bisects redundantly, one candidate/lane,
    //      pure register + shuffle (no LDS in the 50-iter loop, no extra
    //      broadcast barrier) ----
    const float c = (lane < n) ? s_cand[lane] : -INFINITY;
    float tau_lo = rowmax - 1.0f;
    const float tau_hi = rowmax - (1.0f / (float)D);
    float dm = tau_hi - tau_lo;
    const float f_lo = wave_sum(fmaxf(c - tau_lo, 0.0f)) - 1.0f;
    float tau_m = tau_lo;
    for (int it = 0; it < NITER; ++it) {
      dm *= 0.5f;
      tau_m = tau_lo + dm;
      const float f_m = wave_sum(fmaxf(c - tau_m, 0.0f)) - 1.0f;
      if (f_m * f_lo >= 0.0f) tau_lo = tau_m;
    }
    const float sp = wave_sum(fmaxf(c - tau_m, 0.0f));
    tau = tau_m;
    inv = 1.0f / sp;
  } else if (n <= CAP) {
    // ---- mid path: strided over LDS candidate list, all waves redundant ----
    float tau_lo = rowmax - 1.0f;
    const float tau_hi = rowmax - (1.0f / (float)D);
    float dm = tau_hi - tau_lo;
    float s0 = 0.0f;
    for (int i = lane; i < n; i += 64) s0 += fmaxf(s_cand[i] - tau_lo, 0.0f);
    const float f_lo = wave_sum(s0) - 1.0f;
    float tau_m = tau_lo;
    for (int it = 0; it < NITER; ++it) {
      dm *= 0.5f;
      tau_m = tau_lo + dm;
      float fs = 0.0f;
      for (int i = lane; i < n; i += 64) fs += fmaxf(s_cand[i] - tau_m, 0.0f);
      const float f_m = wave_sum(fs) - 1.0f;
      if (f_m * f_lo >= 0.0f) tau_lo = tau_m;
    }
    float sp = 0.0f;
    for (int i = lane; i < n; i += 64) sp += fmaxf(s_cand[i] - tau_m, 0.0f);
    tau = tau_m;
    inv = 1.0f / wave_sum(sp);
  } else {
    // ---- fallback (never expected on Gaussian input): full block-wide
    //      bisection over the register-resident row. __syncthreads here is
    //      fine (drains the prefetch, correctness preserved, just slow). ----
    float tau_lo = rowmax - 1.0f;
    const float tau_hi = rowmax - (1.0f / (float)D);
    float dm = tau_hi - tau_lo;
    auto block_fsum = [&](float tt) -> float {
      float s = 0.0f;
#pragma unroll
      for (int j = 0; j < NV; ++j) {
        s += fmaxf(cur[j].x - tt, 0.0f);
        s += fmaxf(cur[j].y - tt, 0.0f);
        s += fmaxf(cur[j].z - tt, 0.0f);
        s += fmaxf(cur[j].w - tt, 0.0f);
      }
      s = wave_sum(s);
      __syncthreads();
      if (lane == 0) s_red[wid] = s;
      __syncthreads();
      float tot = s_red[0];
#pragma unroll
      for (int j = 1; j < NW; ++j) tot += s_red[j];
      return tot;
    };
    const float f_lo = block_fsum(tau_lo) - 1.0f;
    float tau_m = tau_lo;
    for (int it = 0; it < NITER; ++it) {
      dm *= 0.5f;
      tau_m = tau_lo + dm;
      const float f_m = block_fsum(tau_m) - 1.0f;
      if (f_m * f_lo >= 0.0f) tau_lo = tau_m;
    }
    const float sp = block_fsum(tau_m);
    tau = tau_m;
    inv = 1.0f / sp;
  }

  // ---- epilogue: p = max(x - tau, 0) * inv, straight from registers ----
#pragma unroll
  for (int j = 0; j < FULL4; ++j) {
    float4 o4;
    o4.x = fmaxf(cur[j].x - tau, 0.0f) * inv;
    o4.y = fmaxf(cur[j].y - tau, 0.0f) * inv;
    o4.z = fmaxf(cur[j].z - tau, 0.0f) * inv;
    o4.w = fmaxf(cur[j].w - tau, 0.0f) * inv;
    *reinterpret_cast<float4*>(Or + 4 * t + 4 * BLOCK * j) = o4;
  }
  if (has_rem) {
    float4 o4;
    o4.x = fmaxf(cur[FULL4].x - tau, 0.0f) * inv;
    o4.y = fmaxf(cur[FULL4].y - tau, 0.0f) * inv;
    o4.z = fmaxf(cur[FULL4].z - tau, 0.0f) * inv;
    o4.w = fmaxf(cur[FULL4].w - tau, 0.0f) * inv;
    *reinterpret_cast<float4*>(Or + 4 * BLOCK * FULL4 + 4 * t) = o4;
  }
}

__global__ __launch_bounds__(BLOCK, 4)
void sparsemax_bisect_kernel(const float* __restrict__ X,
                             float* __restrict__ Out,
                             int rows, int nblk) {
  __shared__ float s_cand[CAP];
  __shared__ float s_red[NW];
  __shared__ int s_cnt[2];

  const int t = threadIdx.x;
  const int lane = t & 63;
  const int wid = t >> 6;
  const bool has_rem = (t < REM_THREADS);  // 832 = 13 full waves: wave-uniform

  if (t < 2) s_cnt[t] = 0;  // visible by first bar_lds inside process_row

  float4 A[NV], B[NV];

  long r = blockIdx.x;

  // ---- prologue: load first row directly into A ----
  {
    const float4* X4 = reinterpret_cast<const float4*>(X + r * (long)D);
#pragma unroll
    for (int j = 0; j < FULL4; ++j) A[j] = X4[t + BLOCK * j];
    A[FULL4] = has_rem
                   ? X4[FULL4 * BLOCK + t]
                   : make_float4(-INFINITY, -INFINITY, -INFINITY, -INFINITY);
  }

  // ---- persistent ping-pong over this block's rows ----
  for (;;) {
    long r2 = r + nblk;
    bool pf2 = (r2 < rows);
    process_row(A, B, X + (pf2 ? r2 : r) * (long)D, pf2, Out + r * (long)D,
                s_cand, s_red, s_cnt, 0, t, lane, wid, has_rem);
    if (!pf2) break;
    long r3 = r2 + nblk;
    bool pf3 = (r3 < rows);
    process_row(B, A, X + (pf3 ? r3 : r2) * (long)D, pf3, Out + r2 * (long)D,
                s_cand, s_red, s_cnt, 1, t, lane, wid, has_rem);
    if (!pf3) break;
    r = r3;
  }
}

extern "C" void kernel_launch(void* const* d_in, const int* in_sizes, int n_in,
                              void* d_out, int out_size, void* d_ws, size_t ws_size,
                              hipStream_t stream) {
  const float* X = (const float*)d_in[0];
  float* Out = (float*)d_out;
  const int rows = in_sizes[0] / D;
  const int nblk = rows < PERSIST ? rows : PERSIST;
  hipLaunchKernelGGL(sparsemax_bisect_kernel, dim3(nblk), dim3(BLOCK), 0, stream,
                     X, Out, rows, nblk);
}

// Round 2
// 962.957 us; speedup vs baseline: 1.0066x; 1.0066x over previous
//
#include <hip/hip_runtime.h>
#include <math.h>
#include <stdint.h>

constexpr int D = 32000;
constexpr int BLOCK = 1024;
constexpr int NW = BLOCK / 64;                    // 16 waves
constexpr int FULL4 = D / (4 * BLOCK);            // 7 full float4 rounds
constexpr int REM_THREADS = (D - FULL4 * 4 * BLOCK) / 4;  // 832 = 13 waves
constexpr int NV = FULL4 + 1;                     // 8 float4 per thread
constexpr int CAP = 1024;
constexpr int NITER = 50;
constexpr int PERSIST = 256;                      // 1 persistent block per CU

__device__ __forceinline__ float wave_sum(float s) {
#pragma unroll
  for (int o = 32; o > 0; o >>= 1) s += __shfl_xor(s, o, 64);
  return s;
}

// lgkm-only barrier: LDS visibility without draining vmcnt (keeps the
// global->LDS DMA for the next row in flight).
__device__ __forceinline__ void bar_lds() {
  asm volatile("s_waitcnt lgkmcnt(0)" ::: "memory");
  __builtin_amdgcn_s_barrier();
  asm volatile("" ::: "memory");
}

// Full barrier: waits this wave's DMA + stores, then syncs. After this,
// every wave's DMA has completed -> LDS row buffer is fully populated.
__device__ __forceinline__ void bar_vm() {
  asm volatile("s_waitcnt vmcnt(0) lgkmcnt(0)" ::: "memory");
  __builtin_amdgcn_s_barrier();
  asm volatile("" ::: "memory");
}

typedef __attribute__((address_space(3))) void lds_void;
typedef const __attribute__((address_space(1))) void glb_void;

// Async global->LDS DMA, 16 B per lane. LDS dest must be linear in lane
// order (base + lane*16) -- our layout is exactly that.
__device__ __forceinline__ void gload16(const float* g, float* l) {
  __builtin_amdgcn_global_load_lds((glb_void*)g, (lds_void*)l, 16, 0, 0);
}

__global__ __launch_bounds__(BLOCK, 4)
void sparsemax_bisect_kernel(const float* __restrict__ X,
                             float* __restrict__ Out,
                             int rows, int nblk) {
  __shared__ __attribute__((aligned(16))) float srow[D];  // 128 KB row buffer
  __shared__ float s_cand[CAP];
  __shared__ float s_red[NW];
  __shared__ int s_cnt[2];

  const int t = threadIdx.x;
  const int lane = t & 63;
  const int wid = t >> 6;
  const bool has_rem = (t < REM_THREADS);  // wave-uniform (13 full waves)

  if (t < 2) s_cnt[t] = 0;

  long r = blockIdx.x;

  // ---- prologue: DMA row r into LDS ----
  {
    const float* Xr = X + r * (long)D;
#pragma unroll
    for (int j = 0; j < FULL4; ++j)
      gload16(Xr + 4 * (j * BLOCK + t), srow + 4 * (j * BLOCK + t));
    if (has_rem)
      gload16(Xr + 4 * (FULL4 * BLOCK + t), srow + 4 * (FULL4 * BLOCK + t));
  }
  bar_vm();

  int par = 0;
  for (;;) {
    const long rn = r + nblk;
    const bool pf = (rn < rows);

    // ---- 1) LDS -> registers (pinned: DMA will overwrite srow) ----
    float4 o[NV];
#pragma unroll
    for (int j = 0; j < FULL4; ++j)
      o[j] = *reinterpret_cast<const float4*>(srow + 4 * (j * BLOCK + t));
    o[FULL4] =
        has_rem
            ? *reinterpret_cast<const float4*>(srow + 4 * (FULL4 * BLOCK + t))
            : make_float4(-INFINITY, -INFINITY, -INFINITY, -INFINITY);
#pragma unroll
    for (int j = 0; j < NV; ++j)
      asm volatile("" : "+v"(o[j].x), "+v"(o[j].y), "+v"(o[j].z), "+v"(o[j].w));
    bar_lds();  // all waves finished reading srow

    // ---- 2) issue async DMA of next row into srow (in flight below) ----
    if (pf) {
      const float* Xn = X + rn * (long)D;
#pragma unroll
      for (int j = 0; j < FULL4; ++j)
        gload16(Xn + 4 * (j * BLOCK + t), srow + 4 * (j * BLOCK + t));
      if (has_rem)
        gload16(Xn + 4 * (FULL4 * BLOCK + t), srow + 4 * (FULL4 * BLOCK + t));
    }

    // ---- 3) row max: regs -> wave shuffle -> LDS across 16 waves ----
    float m = -INFINITY;
#pragma unroll
    for (int j = 0; j < NV; ++j)
      m = fmaxf(m, fmaxf(fmaxf(o[j].x, o[j].y), fmaxf(o[j].z, o[j].w)));
#pragma unroll
    for (int off = 32; off > 0; off >>= 1) m = fmaxf(m, __shfl_xor(m, off, 64));
    if (lane == 0) s_red[wid] = m;
    bar_lds();
    float rowmax = s_red[0];
#pragma unroll
    for (int j = 1; j < NW; ++j) rowmax = fmaxf(rowmax, s_red[j]);

    // ---- 4) gather candidates x > rowmax-1 (only these can contribute:
    //         tau_m > tau_lo >= rowmax-1 for all 50 iterations) ----
    const float thresh = rowmax - 1.0f;
#pragma unroll
    for (int j = 0; j < NV; ++j) {
      const float a0 = o[j].x, a1 = o[j].y, a2 = o[j].z, a3 = o[j].w;
      if (a0 > thresh) { int i = atomicAdd(&s_cnt[par], 1); if (i < CAP) s_cand[i] = a0; }
      if (a1 > thresh) { int i = atomicAdd(&s_cnt[par], 1); if (i < CAP) s_cand[i] = a1; }
      if (a2 > thresh) { int i = atomicAdd(&s_cnt[par], 1); if (i < CAP) s_cand[i] = a2; }
      if (a3 > thresh) { int i = atomicAdd(&s_cnt[par], 1); if (i < CAP) s_cand[i] = a3; }
    }
    bar_lds();
    const int n = s_cnt[par];  // block-uniform
    if (t == 0) s_cnt[par ^ 1] = 0;  // other parity; next use after bar_vm

    float tau, inv;
    if (n <= 64) {
      // ---- fast path: one candidate per lane, all waves redundant ----
      const float c = (lane < n) ? s_cand[lane] : -INFINITY;
      float tau_lo = rowmax - 1.0f;
      const float tau_hi = rowmax - (1.0f / (float)D);
      float dm = tau_hi - tau_lo;
      const float f_lo = wave_sum(fmaxf(c - tau_lo, 0.0f)) - 1.0f;
      float tau_m = tau_lo;
      for (int it = 0; it < NITER; ++it) {
        dm *= 0.5f;
        tau_m = tau_lo + dm;
        const float f_m = wave_sum(fmaxf(c - tau_m, 0.0f)) - 1.0f;
        if (f_m * f_lo >= 0.0f) tau_lo = tau_m;
      }
      const float sp = wave_sum(fmaxf(c - tau_m, 0.0f));
      tau = tau_m;
      inv = 1.0f / sp;
    } else if (n <= CAP) {
      // ---- mid path: strided over LDS candidate list ----
      float tau_lo = rowmax - 1.0f;
      const float tau_hi = rowmax - (1.0f / (float)D);
      float dm = tau_hi - tau_lo;
      float s0 = 0.0f;
      for (int i = lane; i < n; i += 64) s0 += fmaxf(s_cand[i] - tau_lo, 0.0f);
      const float f_lo = wave_sum(s0) - 1.0f;
      float tau_m = tau_lo;
      for (int it = 0; it < NITER; ++it) {
        dm *= 0.5f;
        tau_m = tau_lo + dm;
        float fs = 0.0f;
        for (int i = lane; i < n; i += 64) fs += fmaxf(s_cand[i] - tau_m, 0.0f);
        const float f_m = wave_sum(fs) - 1.0f;
        if (f_m * f_lo >= 0.0f) tau_lo = tau_m;
      }
      float sp = 0.0f;
      for (int i = lane; i < n; i += 64) sp += fmaxf(s_cand[i] - tau_m, 0.0f);
      tau = tau_m;
      inv = 1.0f / wave_sum(sp);
    } else {
      // ---- fallback (never expected on Gaussian input): block-wide
      //      bisection over the pinned register copy ----
      float tau_lo = rowmax - 1.0f;
      const float tau_hi = rowmax - (1.0f / (float)D);
      float dm = tau_hi - tau_lo;
      auto block_fsum = [&](float tt) -> float {
        float s = 0.0f;
#pragma unroll
        for (int j = 0; j < NV; ++j) {
          s += fmaxf(o[j].x - tt, 0.0f);
          s += fmaxf(o[j].y - tt, 0.0f);
          s += fmaxf(o[j].z - tt, 0.0f);
          s += fmaxf(o[j].w - tt, 0.0f);
        }
        s = wave_sum(s);
        bar_lds();  // protect s_red reuse
        if (lane == 0) s_red[wid] = s;
        bar_lds();
        float tot = s_red[0];
#pragma unroll
        for (int j = 1; j < NW; ++j) tot += s_red[j];
        return tot;
      };
      const float f_lo = block_fsum(tau_lo) - 1.0f;
      float tau_m = tau_lo;
      for (int it = 0; it < NITER; ++it) {
        dm *= 0.5f;
        tau_m = tau_lo + dm;
        const float f_m = block_fsum(tau_m) - 1.0f;
        if (f_m * f_lo >= 0.0f) tau_lo = tau_m;
      }
      const float sp = block_fsum(tau_m);
      tau = tau_m;
      inv = 1.0f / sp;
    }

    // ---- 6) epilogue: p = max(x - tau, 0) * inv from pinned registers;
    //         stores overlap with the in-flight DMA ----
    float* Or = Out + r * (long)D;
#pragma unroll
    for (int j = 0; j < FULL4; ++j) {
      float4 o4;
      o4.x = fmaxf(o[j].x - tau, 0.0f) * inv;
      o4.y = fmaxf(o[j].y - tau, 0.0f) * inv;
      o4.z = fmaxf(o[j].z - tau, 0.0f) * inv;
      o4.w = fmaxf(o[j].w - tau, 0.0f) * inv;
      *reinterpret_cast<float4*>(Or + 4 * (j * BLOCK + t)) = o4;
    }
    if (has_rem) {
      float4 o4;
      o4.x = fmaxf(o[FULL4].x - tau, 0.0f) * inv;
      o4.y = fmaxf(o[FULL4].y - tau, 0.0f) * inv;
      o4.z = fmaxf(o[FULL4].z - tau, 0.0f) * inv;
      o4.w = fmaxf(o[FULL4].w - tau, 0.0f) * inv;
      *reinterpret_cast<float4*>(Or + 4 * (FULL4 * BLOCK + t)) = o4;
    }

    if (!pf) break;
    r = rn;
    par ^= 1;
    bar_vm();  // DMA for next row complete in all waves; stores ack'd
  }
}

extern "C" void kernel_launch(void* const* d_in, const int* in_sizes, int n_in,
                              void* d_out, int out_size, void* d_ws, size_t ws_size,
                              hipStream_t stream) {
  const float* X = (const float*)d_in[0];
  float* Out = (float*)d_out;
  const int rows = in_sizes[0] / D;
  const int nblk = rows < PERSIST ? rows : PERSIST;
  hipLaunchKernelGGL(sparsemax_bisect_kernel, dim3(nblk), dim3(BLOCK), 0, stream,
                     X, Out, rows, nblk);
}

// Round 3
// 953.967 us; speedup vs baseline: 1.0161x; 1.0094x over previous
//
#include <hip/hip_runtime.h>
#include <math.h>
#include <stdint.h>

constexpr int D = 32000;
constexpr int BLOCK = 1024;
constexpr int NW = BLOCK / 64;                    // 16 waves
constexpr int FULL4 = D / (4 * BLOCK);            // 7 full float4 rounds
constexpr int REM_THREADS = (D - FULL4 * 4 * BLOCK) / 4;  // 832 = 13 waves
constexpr int NV = FULL4 + 1;                     // 8 float4 per thread
constexpr int CAP = 1024;
constexpr int NITER = 50;
constexpr int PERSIST = 256;                      // 1 persistent block per CU

__device__ __forceinline__ float wave_sum(float s) {
#pragma unroll
  for (int o = 32; o > 0; o >>= 1) s += __shfl_xor(s, o, 64);
  return s;
}

// lgkm-only barrier: LDS visibility without draining vmcnt (keeps DMA loads
// and epilogue stores in flight).
__device__ __forceinline__ void bar_lds() {
  asm volatile("s_waitcnt lgkmcnt(0)" ::: "memory");
  __builtin_amdgcn_s_barrier();
  asm volatile("" ::: "memory");
}

typedef __attribute__((address_space(3))) void lds_void;
typedef const __attribute__((address_space(1))) void glb_void;

// Async global->LDS DMA, 16 B per lane (dest = wave-uniform base + lane*16,
// which matches our linear lane-ordered layout; verified absmax=0 in r2).
__device__ __forceinline__ void gload16(const float* g, float* l) {
  __builtin_amdgcn_global_load_lds((glb_void*)g, (lds_void*)l, 16, 0, 0);
}

__global__ __launch_bounds__(BLOCK, 4)
void sparsemax_bisect_kernel(const float* __restrict__ X,
                             float* __restrict__ Out,
                             int rows, int nblk) {
  __shared__ __attribute__((aligned(16))) float srow[D];  // 125 KB row buffer
  __shared__ float s_cand[CAP];
  __shared__ float s_red[NW];
  __shared__ int s_cnt[2];

  const int t = threadIdx.x;
  const int lane = t & 63;
  const int wid = t >> 6;
  const bool has_rem = (t < REM_THREADS);  // wave-uniform (13 full waves)

  if (t < 2) s_cnt[t] = 0;

  long r = blockIdx.x;

  // ---- prologue: DMA row r into LDS, full drain once ----
  {
    const float* Xr = X + r * (long)D;
#pragma unroll
    for (int j = 0; j < FULL4; ++j)
      gload16(Xr + 4 * (j * BLOCK + t), srow + 4 * (j * BLOCK + t));
    if (has_rem)
      gload16(Xr + 4 * (FULL4 * BLOCK + t), srow + 4 * (FULL4 * BLOCK + t));
  }
  asm volatile("s_waitcnt vmcnt(0) lgkmcnt(0)" ::: "memory");
  __builtin_amdgcn_s_barrier();
  asm volatile("" ::: "memory");

  int par = 0;
  for (;;) {
    const long rn = r + nblk;
    const bool pf = (rn < rows);

    // ---- 1) LDS -> registers (pinned). Each wave reads only the srow
    //         region its own DMA wrote, so no cross-wave barrier needed. ----
    float4 o[NV];
#pragma unroll
    for (int j = 0; j < FULL4; ++j)
      o[j] = *reinterpret_cast<const float4*>(srow + 4 * (j * BLOCK + t));
    o[FULL4] =
        has_rem
            ? *reinterpret_cast<const float4*>(srow + 4 * (FULL4 * BLOCK + t))
            : make_float4(-INFINITY, -INFINITY, -INFINITY, -INFINITY);
#pragma unroll
    for (int j = 0; j < NV; ++j)
      asm volatile("" : "+v"(o[j].x), "+v"(o[j].y), "+v"(o[j].z), "+v"(o[j].w));

    // ---- 2) issue async DMA of next row into srow immediately; it streams
    //         underneath ALL compute below and is only waited (counted) at
    //         the end-of-row vmcnt(8). Each wave overwrites only its own
    //         region, already copied to regs above. ----
    if (pf) {
      const float* Xn = X + rn * (long)D;
#pragma unroll
      for (int j = 0; j < FULL4; ++j)
        gload16(Xn + 4 * (j * BLOCK + t), srow + 4 * (j * BLOCK + t));
      if (has_rem)
        gload16(Xn + 4 * (FULL4 * BLOCK + t), srow + 4 * (FULL4 * BLOCK + t));
    }

    // ---- 3) row max: regs -> wave shuffle -> LDS across 16 waves ----
    float m = -INFINITY;
#pragma unroll
    for (int j = 0; j < NV; ++j)
      m = fmaxf(m, fmaxf(fmaxf(o[j].x, o[j].y), fmaxf(o[j].z, o[j].w)));
#pragma unroll
    for (int off = 32; off > 0; off >>= 1) m = fmaxf(m, __shfl_xor(m, off, 64));
    if (lane == 0) s_red[wid] = m;
    bar_lds();
    float rowmax = s_red[0];
#pragma unroll
    for (int j = 1; j < NW; ++j) rowmax = fmaxf(rowmax, s_red[j]);

    // ---- 4) gather candidates x > rowmax-1 (only these can contribute:
    //         tau_m > tau_lo >= rowmax-1 for all 50 iterations) ----
    const float thresh = rowmax - 1.0f;
#pragma unroll
    for (int j = 0; j < NV; ++j) {
      const float a0 = o[j].x, a1 = o[j].y, a2 = o[j].z, a3 = o[j].w;
      if (a0 > thresh) { int i = atomicAdd(&s_cnt[par], 1); if (i < CAP) s_cand[i] = a0; }
      if (a1 > thresh) { int i = atomicAdd(&s_cnt[par], 1); if (i < CAP) s_cand[i] = a1; }
      if (a2 > thresh) { int i = atomicAdd(&s_cnt[par], 1); if (i < CAP) s_cand[i] = a2; }
      if (a3 > thresh) { int i = atomicAdd(&s_cnt[par], 1); if (i < CAP) s_cand[i] = a3; }
    }
    bar_lds();
    const int n = s_cnt[par];        // block-uniform
    if (t == 0) s_cnt[par ^ 1] = 0;  // for the NEXT row; ordered by row-end bar

    float tau, inv;
    if (n <= 64) {
      // ---- fast path: one candidate per lane, all waves redundant ----
      const float c = (lane < n) ? s_cand[lane] : -INFINITY;
      float tau_lo = rowmax - 1.0f;
      const float tau_hi = rowmax - (1.0f / (float)D);
      float dm = tau_hi - tau_lo;
      const float f_lo = wave_sum(fmaxf(c - tau_lo, 0.0f)) - 1.0f;
      float tau_m = tau_lo;
      for (int it = 0; it < NITER; ++it) {
        dm *= 0.5f;
        tau_m = tau_lo + dm;
        const float f_m = wave_sum(fmaxf(c - tau_m, 0.0f)) - 1.0f;
        if (f_m * f_lo >= 0.0f) tau_lo = tau_m;
      }
      const float sp = wave_sum(fmaxf(c - tau_m, 0.0f));
      tau = tau_m;
      inv = 1.0f / sp;
    } else if (n <= CAP) {
      // ---- mid path: strided over LDS candidate list ----
      float tau_lo = rowmax - 1.0f;
      const float tau_hi = rowmax - (1.0f / (float)D);
      float dm = tau_hi - tau_lo;
      float s0 = 0.0f;
      for (int i = lane; i < n; i += 64) s0 += fmaxf(s_cand[i] - tau_lo, 0.0f);
      const float f_lo = wave_sum(s0) - 1.0f;
      float tau_m = tau_lo;
      for (int it = 0; it < NITER; ++it) {
        dm *= 0.5f;
        tau_m = tau_lo + dm;
        float fs = 0.0f;
        for (int i = lane; i < n; i += 64) fs += fmaxf(s_cand[i] - tau_m, 0.0f);
        const float f_m = wave_sum(fs) - 1.0f;
        if (f_m * f_lo >= 0.0f) tau_lo = tau_m;
      }
      float sp = 0.0f;
      for (int i = lane; i < n; i += 64) sp += fmaxf(s_cand[i] - tau_m, 0.0f);
      tau = tau_m;
      inv = 1.0f / wave_sum(sp);
    } else {
      // ---- fallback (never expected on Gaussian input): block-wide
      //      bisection over the pinned register copy ----
      float tau_lo = rowmax - 1.0f;
      const float tau_hi = rowmax - (1.0f / (float)D);
      float dm = tau_hi - tau_lo;
      auto block_fsum = [&](float tt) -> float {
        float s = 0.0f;
#pragma unroll
        for (int j = 0; j < NV; ++j) {
          s += fmaxf(o[j].x - tt, 0.0f);
          s += fmaxf(o[j].y - tt, 0.0f);
          s += fmaxf(o[j].z - tt, 0.0f);
          s += fmaxf(o[j].w - tt, 0.0f);
        }
        s = wave_sum(s);
        bar_lds();
        if (lane == 0) s_red[wid] = s;
        bar_lds();
        float tot = s_red[0];
#pragma unroll
        for (int j = 1; j < NW; ++j) tot += s_red[j];
        return tot;
      };
      const float f_lo = block_fsum(tau_lo) - 1.0f;
      float tau_m = tau_lo;
      for (int it = 0; it < NITER; ++it) {
        dm *= 0.5f;
        tau_m = tau_lo + dm;
        const float f_m = block_fsum(tau_m) - 1.0f;
        if (f_m * f_lo >= 0.0f) tau_lo = tau_m;
      }
      const float sp = block_fsum(tau_m);
      tau = tau_m;
      inv = 1.0f / sp;
    }

    // ---- 5) epilogue: p = max(x - tau, 0) * inv from pinned registers ----
    float* Or = Out + r * (long)D;
#pragma unroll
    for (int j = 0; j < FULL4; ++j) {
      float4 o4;
      o4.x = fmaxf(o[j].x - tau, 0.0f) * inv;
      o4.y = fmaxf(o[j].y - tau, 0.0f) * inv;
      o4.z = fmaxf(o[j].z - tau, 0.0f) * inv;
      o4.w = fmaxf(o[j].w - tau, 0.0f) * inv;
      *reinterpret_cast<float4*>(Or + 4 * (j * BLOCK + t)) = o4;
    }
    if (has_rem) {
      float4 o4;
      o4.x = fmaxf(o[FULL4].x - tau, 0.0f) * inv;
      o4.y = fmaxf(o[FULL4].y - tau, 0.0f) * inv;
      o4.z = fmaxf(o[FULL4].z - tau, 0.0f) * inv;
      o4.w = fmaxf(o[FULL4].w - tau, 0.0f) * inv;
      *reinterpret_cast<float4*>(Or + 4 * (FULL4 * BLOCK + t)) = o4;
    }

    if (!pf) break;
    r = rn;
    par ^= 1;

    // ---- 6) COUNTED end-of-row wait (T4): per-wave outstanding vmem is
    //         [<=8 prev-row stores][8 DMA][8 this-row stores]; waiting
    //         vmcnt(8) retires prev stores + DMA, leaving THIS row's stores
    //         in flight across the whole next row. Remainder-less waves
    //         (13..15) have 7 DMA + 7 stores -> vmcnt(7). lgkmcnt(0) makes
    //         the s_cnt reset visible across the barrier. ----
    if (has_rem) {
      asm volatile("s_waitcnt vmcnt(8) lgkmcnt(0)" ::: "memory");
    } else {
      asm volatile("s_waitcnt vmcnt(7) lgkmcnt(0)" ::: "memory");
    }
    __builtin_amdgcn_s_barrier();
    asm volatile("" ::: "memory");
  }
}

extern "C" void kernel_launch(void* const* d_in, const int* in_sizes, int n_in,
                              void* d_out, int out_size, void* d_ws, size_t ws_size,
                              hipStream_t stream) {
  const float* X = (const float*)d_in[0];
  float* Out = (float*)d_out;
  const int rows = in_sizes[0] / D;
  const int nblk = rows < PERSIST ? rows : PERSIST;
  hipLaunchKernelGGL(sparsemax_bisect_kernel, dim3(nblk), dim3(BLOCK), 0, stream,
                     X, Out, rows, nblk);
}

// Round 4
// 882.824 us; speedup vs baseline: 1.0980x; 1.0806x over previous
//
#include <hip/hip_runtime.h>
#include <math.h>
#include <stdint.h>

constexpr int D = 32000;
constexpr int BLOCK = 1024;
constexpr int NW = BLOCK / 64;                    // 16 waves
constexpr int FULL4 = D / (4 * BLOCK);            // 7 full float4 rounds
constexpr int REM_THREADS = (D - FULL4 * 4 * BLOCK) / 4;  // 832 = 13 waves
constexpr int NV = FULL4 + 1;                     // 8 float4 per thread
constexpr int CAP = 1024;
constexpr int NITER = 50;
constexpr int PERSIST = 256;                      // 1 persistent block per CU

__device__ __forceinline__ float wave_sum(float s) {
#pragma unroll
  for (int o = 32; o > 0; o >>= 1) s += __shfl_xor(s, o, 64);
  return s;
}

// lgkm-only barrier: LDS visibility without draining vmcnt (keeps DMA loads
// and epilogue stores in flight).
__device__ __forceinline__ void bar_lds() {
  asm volatile("s_waitcnt lgkmcnt(0)" ::: "memory");
  __builtin_amdgcn_s_barrier();
  asm volatile("" ::: "memory");
}

typedef __attribute__((address_space(3))) void lds_void;
typedef const __attribute__((address_space(1))) void glb_void;

// Async global->LDS DMA, 16 B per lane (dest = wave-uniform base + lane*16,
// matches our linear lane-ordered layout; verified absmax=0 in r2/r3).
__device__ __forceinline__ void gload16(const float* g, float* l) {
  __builtin_amdgcn_global_load_lds((glb_void*)g, (lds_void*)l, 16, 0, 0);
}

__global__ __launch_bounds__(BLOCK, 4)
void sparsemax_bisect_kernel(const float* __restrict__ X,
                             float* __restrict__ Out,
                             int rows, int nblk) {
  __shared__ __attribute__((aligned(16))) float srow[D];  // 125 KB row buffer
  __shared__ float s_cand[CAP];
  __shared__ float s_red[NW];
  __shared__ int s_cnt[2];

  const int t = threadIdx.x;
  const int lane = t & 63;
  const int wid = t >> 6;
  const bool has_rem = (t < REM_THREADS);  // wave-uniform (13 full waves)

  if (t < 2) s_cnt[t] = 0;

  long r = blockIdx.x;

  // ---- prologue: DMA row r into LDS, full drain once ----
  {
    const float* Xr = X + r * (long)D;
#pragma unroll
    for (int j = 0; j < FULL4; ++j)
      gload16(Xr + 4 * (j * BLOCK + t), srow + 4 * (j * BLOCK + t));
    if (has_rem)
      gload16(Xr + 4 * (FULL4 * BLOCK + t), srow + 4 * (FULL4 * BLOCK + t));
  }
  asm volatile("s_waitcnt vmcnt(0) lgkmcnt(0)" ::: "memory");
  __builtin_amdgcn_s_barrier();
  asm volatile("" ::: "memory");

  int par = 0;
  for (;;) {
    const long rn = r + nblk;
    const bool pf = (rn < rows);

    // ---- 1) LDS -> registers (pinned). Each wave reads only the srow
    //         region its own DMA wrote, so no cross-wave barrier needed. ----
    float4 o[NV];
#pragma unroll
    for (int j = 0; j < FULL4; ++j)
      o[j] = *reinterpret_cast<const float4*>(srow + 4 * (j * BLOCK + t));
    o[FULL4] =
        has_rem
            ? *reinterpret_cast<const float4*>(srow + 4 * (FULL4 * BLOCK + t))
            : make_float4(-INFINITY, -INFINITY, -INFINITY, -INFINITY);
#pragma unroll
    for (int j = 0; j < NV; ++j)
      asm volatile("" : "+v"(o[j].x), "+v"(o[j].y), "+v"(o[j].z), "+v"(o[j].w));

    // ---- 2) issue async DMA of next row into srow immediately; counted
    //         wait at end-of-row leaves it in flight under all compute. ----
    if (pf) {
      const float* Xn = X + rn * (long)D;
#pragma unroll
      for (int j = 0; j < FULL4; ++j)
        gload16(Xn + 4 * (j * BLOCK + t), srow + 4 * (j * BLOCK + t));
      if (has_rem)
        gload16(Xn + 4 * (FULL4 * BLOCK + t), srow + 4 * (FULL4 * BLOCK + t));
    }

    // ---- 3) row max: regs -> wave shuffle -> LDS across 16 waves ----
    float m = -INFINITY;
#pragma unroll
    for (int j = 0; j < NV; ++j)
      m = fmaxf(m, fmaxf(fmaxf(o[j].x, o[j].y), fmaxf(o[j].z, o[j].w)));
#pragma unroll
    for (int off = 32; off > 0; off >>= 1) m = fmaxf(m, __shfl_xor(m, off, 64));
    if (lane == 0) s_red[wid] = m;
    bar_lds();
    float rowmax = s_red[0];
#pragma unroll
    for (int j = 1; j < NW; ++j) rowmax = fmaxf(rowmax, s_red[j]);

    // ---- 4) gather candidates x > rowmax-1 (only these can contribute:
    //         tau >= tau_lo = rowmax-1, all others clamp to 0) ----
    const float thresh = rowmax - 1.0f;
#pragma unroll
    for (int j = 0; j < NV; ++j) {
      const float a0 = o[j].x, a1 = o[j].y, a2 = o[j].z, a3 = o[j].w;
      if (a0 > thresh) { int i = atomicAdd(&s_cnt[par], 1); if (i < CAP) s_cand[i] = a0; }
      if (a1 > thresh) { int i = atomicAdd(&s_cnt[par], 1); if (i < CAP) s_cand[i] = a1; }
      if (a2 > thresh) { int i = atomicAdd(&s_cnt[par], 1); if (i < CAP) s_cand[i] = a2; }
      if (a3 > thresh) { int i = atomicAdd(&s_cnt[par], 1); if (i < CAP) s_cand[i] = a3; }
    }
    bar_lds();
    const int n = s_cnt[par];        // block-uniform
    if (t == 0) s_cnt[par ^ 1] = 0;  // for the NEXT row; ordered by row-end bar

    float tau, inv;
    if (n <= 64) {
      // ---- fast path: CLOSED-FORM sparsemax over <=64 candidates,
      //      one per lane, all waves redundant (no broadcast barrier).
      //      Replaces the 50-iter bisection (312 serial DS ops) with
      //      ~35 DS ops: bitonic sort 21 + scan 6 + pick 1 + sum 6.
      //      The bisection's 50 halvings converge below float32 ulp, so
      //      the closed-form root matches to ~1 ulp of tau. ----
      const float corig = (lane < n) ? s_cand[lane] : -INFINITY;
      float c = corig;
      // bitonic sort, descending across 64 lanes (21 compare-exchanges)
#pragma unroll
      for (int k = 2; k <= 64; k <<= 1) {
#pragma unroll
        for (int j = k >> 1; j > 0; j >>= 1) {
          const float p = __shfl_xor(c, j, 64);
          const bool low = (lane & j) == 0;
          const bool asc = (lane & k) == 0;
          const float mn = fminf(c, p), mx = fmaxf(c, p);
          c = (low == asc) ? mx : mn;  // flipped comparator -> descending
        }
      }
      // inclusive prefix sum of sorted candidates (0 beyond n)
      float P = (lane < n) ? c : 0.0f;
#pragma unroll
      for (int off = 1; off < 64; off <<= 1) {
        const float u = __shfl_up(P, off, 64);
        if (lane >= off) P += u;
      }
      // support size k* = max{ j : c_(j) > (P_j - 1)/j }, then tau
      const float tauj = (P - 1.0f) / (float)(lane + 1);
      const bool valid = (lane < n) && (c > tauj);
      const unsigned long long b = __ballot(valid);
      const int kstar = 64 - __clzll(b);  // highest valid lane + 1 (>=1)
      tau = __shfl(tauj, kstar - 1, 64);
      const float sp = wave_sum(fmaxf(corig - tau, 0.0f));
      inv = 1.0f / sp;
    } else if (n <= CAP) {
      // ---- mid path (rare): exact bisection, strided over LDS list ----
      float tau_lo = rowmax - 1.0f;
      const float tau_hi = rowmax - (1.0f / (float)D);
      float dm = tau_hi - tau_lo;
      float s0 = 0.0f;
      for (int i = lane; i < n; i += 64) s0 += fmaxf(s_cand[i] - tau_lo, 0.0f);
      const float f_lo = wave_sum(s0) - 1.0f;
      float tau_m = tau_lo;
      for (int it = 0; it < NITER; ++it) {
        dm *= 0.5f;
        tau_m = tau_lo + dm;
        float fs = 0.0f;
        for (int i = lane; i < n; i += 64) fs += fmaxf(s_cand[i] - tau_m, 0.0f);
        const float f_m = wave_sum(fs) - 1.0f;
        if (f_m * f_lo >= 0.0f) tau_lo = tau_m;
      }
      float sp = 0.0f;
      for (int i = lane; i < n; i += 64) sp += fmaxf(s_cand[i] - tau_m, 0.0f);
      tau = tau_m;
      inv = 1.0f / wave_sum(sp);
    } else {
      // ---- fallback (never expected on Gaussian input): block-wide
      //      bisection over the pinned register copy ----
      float tau_lo = rowmax - 1.0f;
      const float tau_hi = rowmax - (1.0f / (float)D);
      float dm = tau_hi - tau_lo;
      auto block_fsum = [&](float tt) -> float {
        float s = 0.0f;
#pragma unroll
        for (int j = 0; j < NV; ++j) {
          s += fmaxf(o[j].x - tt, 0.0f);
          s += fmaxf(o[j].y - tt, 0.0f);
          s += fmaxf(o[j].z - tt, 0.0f);
          s += fmaxf(o[j].w - tt, 0.0f);
        }
        s = wave_sum(s);
        bar_lds();
        if (lane == 0) s_red[wid] = s;
        bar_lds();
        float tot = s_red[0];
#pragma unroll
        for (int j = 1; j < NW; ++j) tot += s_red[j];
        return tot;
      };
      const float f_lo = block_fsum(tau_lo) - 1.0f;
      float tau_m = tau_lo;
      for (int it = 0; it < NITER; ++it) {
        dm *= 0.5f;
        tau_m = tau_lo + dm;
        const float f_m = block_fsum(tau_m) - 1.0f;
        if (f_m * f_lo >= 0.0f) tau_lo = tau_m;
      }
      const float sp = block_fsum(tau_m);
      tau = tau_m;
      inv = 1.0f / sp;
    }

    // ---- 5) epilogue: p = max(x - tau, 0) * inv from pinned registers ----
    float* Or = Out + r * (long)D;
#pragma unroll
    for (int j = 0; j < FULL4; ++j) {
      float4 o4;
      o4.x = fmaxf(o[j].x - tau, 0.0f) * inv;
      o4.y = fmaxf(o[j].y - tau, 0.0f) * inv;
      o4.z = fmaxf(o[j].z - tau, 0.0f) * inv;
      o4.w = fmaxf(o[j].w - tau, 0.0f) * inv;
      *reinterpret_cast<float4*>(Or + 4 * (j * BLOCK + t)) = o4;
    }
    if (has_rem) {
      float4 o4;
      o4.x = fmaxf(o[FULL4].x - tau, 0.0f) * inv;
      o4.y = fmaxf(o[FULL4].y - tau, 0.0f) * inv;
      o4.z = fmaxf(o[FULL4].z - tau, 0.0f) * inv;
      o4.w = fmaxf(o[FULL4].w - tau, 0.0f) * inv;
      *reinterpret_cast<float4*>(Or + 4 * (FULL4 * BLOCK + t)) = o4;
    }

    if (!pf) break;
    r = rn;
    par ^= 1;

    // ---- 6) COUNTED end-of-row wait (T4): retire prev stores + this DMA,
    //         leave this row's 8 (or 7) stores in flight across next row ----
    if (has_rem) {
      asm volatile("s_waitcnt vmcnt(8) lgkmcnt(0)" ::: "memory");
    } else {
      asm volatile("s_waitcnt vmcnt(7) lgkmcnt(0)" ::: "memory");
    }
    __builtin_amdgcn_s_barrier();
    asm volatile("" ::: "memory");
  }
}

extern "C" void kernel_launch(void* const* d_in, const int* in_sizes, int n_in,
                              void* d_out, int out_size, void* d_ws, size_t ws_size,
                              hipStream_t stream) {
  const float* X = (const float*)d_in[0];
  float* Out = (float*)d_out;
  const int rows = in_sizes[0] / D;
  const int nblk = rows < PERSIST ? rows : PERSIST;
  hipLaunchKernelGGL(sparsemax_bisect_kernel, dim3(nblk), dim3(BLOCK), 0, stream,
                     X, Out, rows, nblk);
}